// Round 15
// baseline (229.440 us; speedup 1.0000x reference)
//
#include <hip/hip_runtime.h>
#include <hip/hip_bf16.h>
#include <cstdint>

// ---------------------------------------------------------------------------
// Hamilton_V5  R24: attack the invariant ~130us OUTSIDE launch3.
//  - Theory: the 64x64-tile GEMMs (Hfwd/A1/A2) run at 30-100 TF (m102 small-N
//    curve) because each wave does only 4 mfma per barrier. ~80us of the rest.
//  - gemm128_body: 128x128 tile, 256 thr / 4 waves (2x2), wave tile 64x64 =
//    4x4 mfma 16x16x32 per step (4x mfma/barrier). Triple-buffered LDS
//    (3 x 8KB A + 3 x 8KB B = 48KB), depth-2 prefetch, counted vmcnt(4).
//    Hfwd 160 blocks, A1 128, A2 256 (was 640/512/1024).
//  - All aw3t (1024 blocks) moved to L0 (depends only on Aw3 input).
//    L1 = pure Hfwd+A1 (288 blocks); L2 = A2 + hgrad (1280).
//  - launch3 byte-identical to R23 = control (~96us expected).
// ---------------------------------------------------------------------------

typedef __bf16 bf16_t;
typedef __bf16 bf16x4_t __attribute__((ext_vector_type(4)));
typedef __bf16 bf16x8_t __attribute__((ext_vector_type(8)));
typedef float f32x4_t __attribute__((ext_vector_type(4)));
typedef float f32x16_t __attribute__((ext_vector_type(16)));
typedef int intx4_t __attribute__((ext_vector_type(4)));
typedef int intx8_t __attribute__((ext_vector_type(8)));

#define DIMD 128
#define NROW 4096
#define SMEM_G64 24576     // gemm64 3-buf (hbwd)
#define SMEM_G128 49152    // gemm128 3-buf (3x4096x2 x2)
#define SMEM_L0 16896      // aw3t transpose buffer
#define SMEM3_BYTES 32768  // a3: 2 x 16384 (A tiles); hbwd uses 24576

// branchless tanh: t=2^(2x*log2e); tanh=1-2/(t+1).
__device__ __forceinline__ float fast_tanh(float x) {
  float t = __builtin_amdgcn_exp2f(x * 2.8853900817779268f);
  return 1.f - 2.f * __builtin_amdgcn_rcpf(t + 1.f);
}

// f32 -> fp8 e4m3 (OCP), RNE+sat via HW cvt
__device__ __forceinline__ uint8_t to_fp8(float x) {
  return (uint8_t)(__builtin_amdgcn_cvt_pk_fp8_f32(x, x, 0, false) & 0xff);
}

// pack 4 f32 -> 4 fp8 bytes (byte0=a .. byte3=d) via 2 HW cvt_pk
__device__ __forceinline__ uint32_t pk4_fp8(float a, float b, float c,
                                            float d) {
  uint32_t lo = (uint32_t)__builtin_amdgcn_cvt_pk_fp8_f32(a, b, 0, false);
  return (uint32_t)__builtin_amdgcn_cvt_pk_fp8_f32(c, d, lo, true);
}

// async global->LDS, 16B per lane; LDS dest = wave-uniform base + lane*16
__device__ __forceinline__ void g2l16(const void* gp, void* lp) {
  __builtin_amdgcn_global_load_lds(
      reinterpret_cast<__attribute__((address_space(1))) void*>(
          reinterpret_cast<uintptr_t>(gp)),
      reinterpret_cast<__attribute__((address_space(3))) void*>(
          reinterpret_cast<uintptr_t>(lp)),
      16, 0, 0);
}

// DPP accumulating add (VALU pipe -- no LDS). bound_ctrl=1 => 0-fill.
template <int CTRL>
__device__ __forceinline__ float dpp_addf(float v) {
  return v + __int_as_float(__builtin_amdgcn_update_dpp(
                 0, __float_as_int(v), CTRL, 0xf, 0xf, true));
}
// sum over each 32-lane half; result in lane 31 (half 0) / lane 63 (half 1).
__device__ __forceinline__ float dpp_sum32(float v) {
  v = dpp_addf<0x111>(v);  // row_shr:1
  v = dpp_addf<0x112>(v);  // row_shr:2
  v = dpp_addf<0x114>(v);  // row_shr:4
  v = dpp_addf<0x118>(v);  // row_shr:8  -> lane15/31/47/63 = row sums
  v = dpp_addf<0x142>(v);  // row_bcast15 -> lane31/63 = 32-lane sums
  return v;
}

// ---------------------------------------------------------------------------
// bf16 GEMM, 64x64 tile, BK=32, 4 waves 2x2 -- retained for Hbwd (EPI 1).
// ---------------------------------------------------------------------------
template <int EPI>
__device__ __forceinline__ void gemm64_body(char* smem, int bx, int by,
                                            const bf16_t* A, int lda,
                                            const bf16_t* B, int ldb, int K,
                                            const float* bias, void* outp,
                                            int ldo) {
  constexpr int BK = 32;
  bf16_t* As = (bf16_t*)smem;   // 3 x 64*32
  bf16_t* Bs = As + 3 * 2048;   // 3 x 64*32
  const int NT = K / BK;

  const int m0 = bx * 64;
  const int n0 = by * 64;
  const int tid = threadIdx.x;
  const int wave = tid >> 6;
  const int lane = tid & 63;
  const int wm = wave >> 1;
  const int wn = wave & 1;

  const int sr = lane >> 2;
  const int sk = (((lane & 3) ^ ((sr >> 1) & 3)) * 8);
  const int fr = lane & 15;
  const int fk = (((lane >> 4) ^ ((fr >> 1) & 3)) * 8);
  const int rb = wave * 16;  // each wave stages 16 rows of A and B

  const bf16_t* Ag = A + (size_t)(m0 + rb + sr) * lda + sk;
  const bf16_t* Bg = B + (size_t)(n0 + rb + sr) * ldb + sk;

#define G64_STAGE(buf, k0)                              \
  do {                                                  \
    g2l16(Ag + (k0), As + (buf) * 2048 + rb * BK);      \
    g2l16(Bg + (k0), Bs + (buf) * 2048 + rb * BK);      \
  } while (0)

  f32x4_t acc[2][2] = {};

  G64_STAGE(0, 0);
  G64_STAGE(1, BK);
  asm volatile("s_waitcnt vmcnt(2)" ::: "memory");
  __builtin_amdgcn_s_barrier();
  asm volatile("" ::: "memory");

  for (int t = 0; t < NT; ++t) {
    if (t + 2 < NT) G64_STAGE((t + 2) % 3, (t + 2) * BK);
    const bf16_t* Ab = As + (t % 3) * 2048;
    const bf16_t* Bb = Bs + (t % 3) * 2048;

    bf16x8_t af[2], bb[2];
#pragma unroll
    for (int u = 0; u < 2; ++u) {
      af[u] = *(const bf16x8_t*)(Ab + (wm * 32 + u * 16 + fr) * BK + fk);
      bb[u] = *(const bf16x8_t*)(Bb + (wn * 32 + u * 16 + fr) * BK + fk);
    }
#pragma unroll
    for (int i = 0; i < 2; ++i)
#pragma unroll
      for (int j = 0; j < 2; ++j)
        acc[i][j] = __builtin_amdgcn_mfma_f32_16x16x32_bf16(af[i], bb[j],
                                                            acc[i][j], 0, 0, 0);
    if (t < NT - 1) {
      if (t + 2 < NT)
        asm volatile("s_waitcnt vmcnt(2)" ::: "memory");
      else
        asm volatile("s_waitcnt vmcnt(0)" ::: "memory");
      __builtin_amdgcn_s_barrier();
      asm volatile("" ::: "memory");
    }
  }
#undef G64_STAGE

  // C/D layout (m89): col = lane&15, row = (lane>>4)*4 + reg
#pragma unroll
  for (int i = 0; i < 2; ++i) {
    const int row = m0 + wm * 32 + i * 16 + (lane >> 4) * 4;
#pragma unroll
    for (int j = 0; j < 2; ++j) {
      const int col = n0 + wn * 32 + j * 16 + fr;
      if constexpr (EPI == 1) {
        float* O = (float*)outp;
        const bool dx = (n0 < DIMD);
#pragma unroll
        for (int r = 0; r < 4; ++r) {
          const size_t idx = (size_t)(row + r) * ldo + col;
          if (dx) O[idx] = acc[i][j][r];
          else atomicAdd(&O[idx], -acc[i][j][r]);  // dv_H shares with dvA
        }
      } else {  // EPI 0 (unused here, kept for completeness)
        bf16_t* O = (bf16_t*)outp;
        const float b = bias ? bias[col] : 0.f;
#pragma unroll
        for (int r = 0; r < 4; ++r)
          O[(size_t)(row + r) * ldo + col] = (bf16_t)fast_tanh(acc[i][j][r] + b);
      }
    }
  }
}

// ---------------------------------------------------------------------------
// bf16 GEMM, 128x128 tile, BK=32, 4 waves 2x2 (wave tile 64x64 = 4x4 mfma
// 16x16x32 per step -- 4x the mfma/barrier of gemm64).
// Triple-buffered LDS (3 x 8KB per operand), depth-2 prefetch, vmcnt(4).
// EPI 0: bf16 tanh(C+b); EPI 3: fp8 x64 row-major.
// ---------------------------------------------------------------------------
template <int EPI>
__device__ __forceinline__ void gemm128_body(char* smem, int bx, int by,
                                             const bf16_t* A, int lda,
                                             const bf16_t* B, int ldb, int K,
                                             const float* bias, void* outp,
                                             int ldo) {
  constexpr int BK = 32;
  bf16_t* As = (bf16_t*)smem;   // 3 x 128*32
  bf16_t* Bs = As + 3 * 4096;   // 3 x 128*32
  const int NT = K / BK;

  const int m0 = bx * 128;
  const int n0 = by * 128;
  const int tid = threadIdx.x;
  const int wave = tid >> 6;
  const int lane = tid & 63;
  const int wm = wave >> 1;
  const int wn = wave & 1;

  const int sr = lane >> 2;
  const int sk = (((lane & 3) ^ ((sr >> 1) & 3)) * 8);
  const int fr = lane & 15;
  const int fk = (((lane >> 4) ^ ((fr >> 1) & 3)) * 8);
  const int rb = wave * 32;  // each wave stages 32 rows of A and B (2 ops ea)

  const bf16_t* Ag = A + (size_t)(m0 + rb + sr) * lda + sk;
  const bf16_t* Bg = B + (size_t)(n0 + rb + sr) * ldb + sk;

#define G128_STAGE(buf, k0)                                                  \
  do {                                                                       \
    g2l16(Ag + (k0), As + (buf) * 4096 + rb * BK);                           \
    g2l16(Ag + (size_t)16 * lda + (k0), As + (buf) * 4096 + (rb + 16) * BK); \
    g2l16(Bg + (k0), Bs + (buf) * 4096 + rb * BK);                           \
    g2l16(Bg + (size_t)16 * ldb + (k0), Bs + (buf) * 4096 + (rb + 16) * BK); \
  } while (0)

  f32x4_t acc[4][4] = {};

  G128_STAGE(0, 0);
  G128_STAGE(1, BK);
  asm volatile("s_waitcnt vmcnt(4)" ::: "memory");
  __builtin_amdgcn_s_barrier();
  asm volatile("" ::: "memory");

  for (int t = 0; t < NT; ++t) {
    if (t + 2 < NT) G128_STAGE((t + 2) % 3, (t + 2) * BK);
    const bf16_t* Ab = As + (t % 3) * 4096;
    const bf16_t* Bb = Bs + (t % 3) * 4096;

    bf16x8_t af[4], bb[4];
#pragma unroll
    for (int u = 0; u < 4; ++u) {
      af[u] = *(const bf16x8_t*)(Ab + (wm * 64 + u * 16 + fr) * BK + fk);
      bb[u] = *(const bf16x8_t*)(Bb + (wn * 64 + u * 16 + fr) * BK + fk);
    }
#pragma unroll
    for (int i = 0; i < 4; ++i)
#pragma unroll
      for (int j = 0; j < 4; ++j)
        acc[i][j] = __builtin_amdgcn_mfma_f32_16x16x32_bf16(af[i], bb[j],
                                                            acc[i][j], 0, 0, 0);
    if (t < NT - 1) {
      if (t + 2 < NT)
        asm volatile("s_waitcnt vmcnt(4)" ::: "memory");
      else
        asm volatile("s_waitcnt vmcnt(0)" ::: "memory");
      __builtin_amdgcn_s_barrier();
      asm volatile("" ::: "memory");
    }
  }
#undef G128_STAGE

  // C/D layout (m89): col = lane&15, row = (lane>>4)*4 + reg
#pragma unroll
  for (int i = 0; i < 4; ++i) {
    const int row = m0 + wm * 64 + i * 16 + (lane >> 4) * 4;
#pragma unroll
    for (int j = 0; j < 4; ++j) {
      const int col = n0 + wn * 64 + j * 16 + fr;
      if constexpr (EPI == 0) {
        bf16_t* O = (bf16_t*)outp;
        const float b = bias[col];
#pragma unroll
        for (int r = 0; r < 4; ++r)
          O[(size_t)(row + r) * ldo + col] = (bf16_t)fast_tanh(acc[i][j][r] + b);
      } else {  // EPI 3: fp8 x64 row-major
        uint8_t* O = (uint8_t*)outp;
        const float b = bias[col];
#pragma unroll
        for (int r = 0; r < 4; ++r)
          O[(size_t)(row + r) * ldo + col] =
              to_fp8(64.f * fast_tanh(acc[i][j][r] + b));
      }
    }
  }
}

// ---------------------------------------------------------------------------
// A3 fused GEMM, MX-fp8 (R23, unchanged = control): 256 thr / 4 waves,
// 128x128, BK=128; A LDS double-buffer, B JIT fragment loads; 8 barriers.
// ---------------------------------------------------------------------------
__device__ __forceinline__ void a3_body(char* smem, int bx, int by,
                                        const uint8_t* Arow,
                                        const uint8_t* BF, float* out,
                                        const float* ab3, const float* uvec) {
  constexpr int NT = 8;          // K=1024 / BK=128
  uint8_t* As = (uint8_t*)smem;  // 2 x 16384

  const int tid = threadIdx.x;
  const int wave = tid >> 6;  // 0..3
  const int lane = tid & 63;
  const int wm = wave >> 1;   // 0..1 : 64-row strip
  const int wn = wave & 1;    // 0..1 : 64-col strip
  const int rl = lane & 31;
  const int c0 = lane >> 5;
  const int m0 = bx * 128;
  const int n0 = by * 128;

  const int sr = lane >> 2;  // 0..15
  const int sk = ((lane & 3) ^ ((sr >> 1) & 3)) * 16;
  const uint8_t* Ag = Arow + (size_t)(m0 + wave * 32 + sr) * 1024 + sk;
  const int lbase = wave * 2048;  // wave's 32 rows = 2KB within each half

#define A3_STAGE(buf, t)                                                     \
  do {                                                                       \
    _Pragma("unroll") for (int h_ = 0; h_ < 2; ++h_) {                       \
      g2l16(Ag + (size_t)(2 * (t) + h_) * 64,                                \
            As + (buf)*16384 + h_ * 8192 + lbase);                           \
      g2l16(Ag + 16 * 1024 + (size_t)(2 * (t) + h_) * 64,                    \
            As + (buf)*16384 + h_ * 8192 + lbase + 1024);                    \
    }                                                                        \
  } while (0)

  const uint8_t* Bg0 = BF + (size_t)(by * 4 + wn * 2 + 0) * 16 * 2048 + lane * 32;
  const uint8_t* Bg1 = BF + (size_t)(by * 4 + wn * 2 + 1) * 16 * 2048 + lane * 32;

  f32x16_t acc[2][2] = {};

  A3_STAGE(0, 0);
  asm volatile("s_waitcnt vmcnt(0)" ::: "memory");
  __builtin_amdgcn_s_barrier();
  asm volatile("" ::: "memory");

  const int w = (rl >> 1) & 3;
  const int sLo = ((2 * c0) ^ w) * 16;
  const int sHi = ((2 * c0 + 1) ^ w) * 16;

#pragma unroll
  for (int t = 0; t < NT; ++t) {
    if (t + 1 < NT) A3_STAGE((t + 1) & 1, t + 1);
    const uint8_t* Ab = As + (t & 1) * 16384;
#pragma unroll
    for (int kh = 0; kh < 2; ++kh) {
      const size_t ck = (size_t)(2 * t + kh) * 2048;
      intx8_t b0, b1;
      *(intx4_t*)&b0 = *(const intx4_t*)(Bg0 + ck);
      *((intx4_t*)&b0 + 1) = *(const intx4_t*)(Bg0 + ck + 16);
      *(intx4_t*)&b1 = *(const intx4_t*)(Bg1 + ck);
      *((intx4_t*)&b1 + 1) = *(const intx4_t*)(Bg1 + ck + 16);
#pragma unroll
      for (int i = 0; i < 2; ++i) {
        const int ra = (wm * 64 + i * 32 + rl) * 64;
        intx8_t af;
        *(intx4_t*)&af = *(const intx4_t*)(Ab + kh * 8192 + ra + sLo);
        *((intx4_t*)&af + 1) = *(const intx4_t*)(Ab + kh * 8192 + ra + sHi);
        acc[i][0] = __builtin_amdgcn_mfma_scale_f32_32x32x64_f8f6f4(
            af, b0, acc[i][0], 0, 0, 0, 0x79797979, 0, 0x79797979);
        acc[i][1] = __builtin_amdgcn_mfma_scale_f32_32x32x64_f8f6f4(
            af, b1, acc[i][1], 0, 0, 0, 0x79797979, 0, 0x79797979);
      }
    }
    if (t < NT - 1) {
      asm volatile("s_waitcnt vmcnt(0)" ::: "memory");
      __builtin_amdgcn_s_barrier();
      asm volatile("" ::: "memory");
    }
  }
#undef A3_STAGE

  // epilogue: C/D col = lane&31, row = (reg&3)+8*(reg>>2)+4*(lane>>5).
  const int q = lane >> 5;
  float uu[2], b3[2];
#pragma unroll
  for (int j = 0; j < 2; ++j) {
    uu[j] = uvec[wn * 64 + j * 32 + rl];
    b3[j] = ab3[n0 + wn * 64 + j * 32 + rl];
  }
  const int ocol = 128 + by;
#pragma unroll
  for (int i = 0; i < 2; ++i) {
    float s16[16];
#pragma unroll
    for (int r = 0; r < 16; ++r)
      s16[r] = fast_tanh(acc[i][0][r] + b3[0]) * uu[0] +
               fast_tanh(acc[i][1][r] + b3[1]) * uu[1];
#pragma unroll
    for (int r = 0; r < 16; ++r) s16[r] = dpp_sum32(s16[r]);
    if (rl == 31) {
      const int rowb = m0 + wm * 64 + i * 32 + 4 * q;
#pragma unroll
      for (int r = 0; r < 16; ++r)
        atomicAdd(&out[(size_t)(rowb + (r & 3) + 8 * (r >> 2)) * 256 + ocol],
                  s16[r]);
    }
  }
}

// ---------------------------------------------------------------------------
// transposes / cvt helpers
// ---------------------------------------------------------------------------
__device__ __forceinline__ void tcvt_body(char* smem, const float* in,
                                          bf16_t* out, int R, int C, int bx,
                                          int by) {
  float(*t)[33] = (float(*)[33])smem;  // 4224 B
  const int c0 = bx * 32;
  const int r0 = by * 32;
  const int tx = threadIdx.x & 31;
  const int ty = threadIdx.x >> 5;
#pragma unroll
  for (int k = 0; k < 4; ++k)
    t[ty + k * 8][tx] = in[(size_t)(r0 + ty + k * 8) * C + c0 + tx];
  __syncthreads();
#pragma unroll
  for (int k = 0; k < 4; ++k)
    out[(size_t)(c0 + ty + k * 8) * R + r0 + tx] = (bf16_t)t[tx][ty + k * 8];
}

// Aw3 (1024 x 16384) -> fp8 x64, FRAGMENT-MAJOR (Aw3T8F).
__device__ __forceinline__ void aw3t_body(char* smem, const float* Aw3,
                                          uint8_t* Aw3T8F, int b) {
  uint32_t(*T)[33] = (uint32_t(*)[33])smem;  // 16896 B
  const int ct = b & 127;
  const int rt = b >> 7;
  const size_t c0 = (size_t)ct * 128;
  const int r0 = rt * 128;
  const int tx = threadIdx.x & 31;  // col-chunk (4 f32)
  const int g = threadIdx.x >> 5;   // 0..7 row-group
#pragma unroll
  for (int k = 0; k < 4; ++k) {
    const int rr = r0 + 4 * g + 32 * k;
    const float4 v0 = *(const float4*)(Aw3 + (size_t)(rr + 0) * 16384 + c0 + 4 * tx);
    const float4 v1 = *(const float4*)(Aw3 + (size_t)(rr + 1) * 16384 + c0 + 4 * tx);
    const float4 v2 = *(const float4*)(Aw3 + (size_t)(rr + 2) * 16384 + c0 + 4 * tx);
    const float4 v3 = *(const float4*)(Aw3 + (size_t)(rr + 3) * 16384 + c0 + 4 * tx);
    const int r4 = g + 8 * k;  // row/4 within tile (k-dim of output)
    T[4 * tx + 0][r4] = pk4_fp8(64.f * v0.x, 64.f * v1.x, 64.f * v2.x, 64.f * v3.x);
    T[4 * tx + 1][r4] = pk4_fp8(64.f * v0.y, 64.f * v1.y, 64.f * v2.y, 64.f * v3.y);
    T[4 * tx + 2][r4] = pk4_fp8(64.f * v0.z, 64.f * v1.z, 64.f * v2.z, 64.f * v3.z);
    T[4 * tx + 3][r4] = pk4_fp8(64.f * v0.w, 64.f * v1.w, 64.f * v2.w, 64.f * v3.w);
  }
  __syncthreads();
  const int kb = (rt << 1) + (tx >> 4);     // k-block (64)
  const int khalf = (tx >> 3) & 1;          // k-half (32)
  const int kin = (tx & 7) << 2;            // k%32 (4-aligned)
#pragma unroll
  for (int k2 = 0; k2 < 16; ++k2) {
    const int cc = g + 8 * k2;
    const int cb = (ct << 2) + (cc >> 5);
    const int cin = cc & 31;
    *(uint32_t*)(Aw3T8F + (size_t)(cb * 16 + kb) * 2048 +
                 (khalf * 32 + cin) * 32 + kin) = T[cc][tx];
  }
}

// one wave handles one row: pre2 = h.Hw2; w_j = s*Hw2_j*(1-h_j^2)
__device__ __forceinline__ void hgrad_row(int row, const bf16_t* h,
                                          const float* Hw2, const float* Hb2,
                                          bf16_t* wout) {
  const int lane = threadIdx.x & 63;
  float hv[10], wv[10];
  float pre2 = 0.f;
#pragma unroll
  for (int t = 0; t < 10; ++t) {
    const int j = lane + t * 64;
    hv[t] = (float)h[(size_t)row * 640 + j];
    wv[t] = Hw2[j];
    pre2 += hv[t] * wv[t];
  }
#pragma unroll
  for (int d = 1; d < 64; d <<= 1) pre2 += __shfl_xor(pre2, d, 64);
  const float y = fast_tanh(pre2 + Hb2[0]);
  const float s = 1.f - y * y;
#pragma unroll
  for (int t = 0; t < 10; ++t) {
    const int j = lane + t * 64;
    wout[(size_t)row * 640 + j] = (bf16_t)(s * wv[t] * (1.f - hv[t] * hv[t]));
  }
}

// ---------------------------------------------------------------------------
// L0: inp cvt (1024) + Hw1T (160) + Aw1T (64) + Aw2T (512) + Hw1_bf cvt (160)
//     + zero-out (1024) + aw3t ALL (1024) = 3968 blocks
// ---------------------------------------------------------------------------
__global__ __launch_bounds__(256) void launch0(
    const float* __restrict__ inp, bf16_t* __restrict__ inp_bf,
    const float* __restrict__ Hw1, bf16_t* __restrict__ Hw1T,
    bf16_t* __restrict__ Hw1_bf, const float* __restrict__ Aw1,
    bf16_t* __restrict__ Aw1T, const float* __restrict__ Aw2,
    bf16_t* __restrict__ Aw2T, float* __restrict__ out,
    const float* __restrict__ Aw3, uint8_t* __restrict__ Aw3T8F) {
  __shared__ __align__(16) char smem[SMEM_L0];
  int b = blockIdx.x;
  if (b < 1024) {
    const int i = b * 256 + threadIdx.x;
    const float4 v = ((const float4*)inp)[i];
    bf16x4_t o = {(bf16_t)v.x, (bf16_t)v.y, (bf16_t)v.z, (bf16_t)v.w};
    ((bf16x4_t*)inp_bf)[i] = o;
  } else if (b < 1184) {
    int s = b - 1024;
    tcvt_body(smem, Hw1, Hw1T, 256, 640, s % 20, s / 20);
  } else if (b < 1248) {
    int s = b - 1184;
    tcvt_body(smem, Aw1, Aw1T, 128, 512, s % 16, s / 16);
  } else if (b < 1760) {
    int s = b - 1248;
    tcvt_body(smem, Aw2, Aw2T, 512, 1024, s % 32, s / 32);
  } else if (b < 1920) {
    const int i = (b - 1760) * 256 + threadIdx.x;
    const float4 v = ((const float4*)Hw1)[i];
    bf16x4_t o = {(bf16_t)v.x, (bf16_t)v.y, (bf16_t)v.z, (bf16_t)v.w};
    ((bf16x4_t*)Hw1_bf)[i] = o;
  } else if (b < 2944) {
    const int i = (b - 1920) * 256 + threadIdx.x;
    ((float4*)out)[i] = make_float4(0.f, 0.f, 0.f, 0.f);
  } else {
    aw3t_body(smem, Aw3, Aw3T8F, b - 2944);  // all 1024 tiles
  }
}

// ---------------------------------------------------------------------------
// L1: Hfwd 128^2 (160) + A1 128^2 (128) = 288 blocks (pure GEMM)
// ---------------------------------------------------------------------------
__global__ __launch_bounds__(256, 3) void launch1(
    const bf16_t* __restrict__ inp_bf, const bf16_t* __restrict__ Hw1T,
    const float* __restrict__ Hb1, bf16_t* __restrict__ h_bf,
    const bf16_t* __restrict__ Aw1T, const float* __restrict__ Ab1,
    bf16_t* __restrict__ h1_bf) {
  __shared__ __align__(16) char smem[SMEM_G128];
  const int b = blockIdx.x;
  if (b < 160) {
    gemm128_body<0>(smem, b % 32, b / 32, inp_bf, 256, Hw1T, 256, 256, Hb1,
                    h_bf, 640);
  } else {
    const int i = b - 160;
    gemm128_body<0>(smem, i % 32, i / 32, inp_bf, 256, Aw1T, 128, 128, Ab1,
                    h1_bf, 512);
  }
}

// ---------------------------------------------------------------------------
// L2: A2->fp8 128^2 (256) + hgrad (1024) = 1280 blocks
// ---------------------------------------------------------------------------
__global__ __launch_bounds__(256, 3) void launch2(
    const bf16_t* __restrict__ h1_bf, const bf16_t* __restrict__ Aw2T,
    const float* __restrict__ Ab2, uint8_t* __restrict__ h2_f8,
    const bf16_t* __restrict__ h_bf, const float* __restrict__ Hw2,
    const float* __restrict__ Hb2, bf16_t* __restrict__ w_bf) {
  __shared__ __align__(16) char smem[SMEM_G128];
  const int b = blockIdx.x;
  if (b < 256) {
    gemm128_body<3>(smem, b % 32, b / 32, h1_bf, 512, Aw2T, 512, 512, Ab2,
                    h2_f8, 1024);
  } else {
    const int row = (b - 256) * 4 + (threadIdx.x >> 6);
    hgrad_row(row, h_bf, Hw2, Hb2, w_bf);
  }
}

// ---------------------------------------------------------------------------
// L3 (256 threads): Hbwd 64^2 4-wave (256) + A3 hybrid 128x128 (4096) = 4352.
// A3 swizzle: hardware XCD = p%8; each XCD owns 16 contiguous by values.
// ---------------------------------------------------------------------------
__global__ __launch_bounds__(256, 4) void launch3(
    const bf16_t* __restrict__ w_bf, const bf16_t* __restrict__ Hw1_bf,
    float* __restrict__ out, const uint8_t* __restrict__ h2_f8,
    const uint8_t* __restrict__ Aw3T8F, const float* __restrict__ Ab3,
    const float* __restrict__ uvec) {
  __shared__ __align__(16) char smem[SMEM3_BYTES];
  const int b = blockIdx.x;
  if (b < 256) {
    gemm64_body<1>(smem, b % 64, b / 64, w_bf, 640, Hw1_bf, 640, 640, nullptr,
                   out, 256);
  } else {
    const int p = b - 256;                          // 0..4095; hw XCD = p % 8
    const int by = (p & 7) * 16 + ((p >> 3) & 15);  // 0..127
    const int bx = p >> 7;                          // 0..31
    a3_body(smem, bx, by, h2_f8, Aw3T8F, out, Ab3, uvec);
  }
}

// ---------------------------------------------------------------------------
extern "C" void kernel_launch(void* const* d_in, const int* in_sizes, int n_in,
                              void* d_out, int out_size, void* d_ws,
                              size_t ws_size, hipStream_t stream) {
  (void)in_sizes; (void)n_in; (void)out_size; (void)ws_size;
  const float* inp = (const float*)d_in[1];
  const float* Hw1 = (const float*)d_in[2];
  const float* Hb1 = (const float*)d_in[3];
  const float* Hw2 = (const float*)d_in[4];
  const float* Hb2 = (const float*)d_in[5];
  const float* Aw1 = (const float*)d_in[6];
  const float* Ab1 = (const float*)d_in[7];
  const float* Aw2 = (const float*)d_in[8];
  const float* Ab2 = (const float*)d_in[9];
  const float* Aw3 = (const float*)d_in[10];
  const float* Ab3 = (const float*)d_in[11];
  const float* u = (const float*)d_in[12];
  float* out = (float*)d_out;

  char* ws = (char*)d_ws;
  bf16_t* inp_bf = (bf16_t*)ws;    ws += (size_t)NROW * 256 * 2;
  bf16_t* Hw1_bf = (bf16_t*)ws;    ws += (size_t)256 * 640 * 2;
  bf16_t* Hw1T = (bf16_t*)ws;      ws += (size_t)640 * 256 * 2;
  bf16_t* Aw1T = (bf16_t*)ws;      ws += (size_t)512 * 128 * 2;
  bf16_t* Aw2T = (bf16_t*)ws;      ws += (size_t)1024 * 512 * 2;
  uint8_t* Aw3T8F = (uint8_t*)ws;  ws += (size_t)16384 * 1024;
  bf16_t* h_bf = (bf16_t*)ws;      ws += (size_t)NROW * 640 * 2;
  bf16_t* w_bf = (bf16_t*)ws;      ws += (size_t)NROW * 640 * 2;
  bf16_t* h1_bf = (bf16_t*)ws;     ws += (size_t)NROW * 512 * 2;
  uint8_t* h2_f8 = (uint8_t*)ws;   ws += (size_t)NROW * 1024;

  launch0<<<3968, 256, 0, stream>>>(inp, inp_bf, Hw1, Hw1T, Hw1_bf, Aw1, Aw1T,
                                    Aw2, Aw2T, out, Aw3, Aw3T8F);
  launch1<<<288, 256, 0, stream>>>(inp_bf, Hw1T, Hb1, h_bf, Aw1T, Ab1, h1_bf);
  launch2<<<1280, 256, 0, stream>>>(h1_bf, Aw2T, Ab2, h2_f8, h_bf, Hw2, Hb2,
                                    w_bf);
  launch3<<<4352, 256, 0, stream>>>(w_bf, Hw1_bf, out, h2_f8, Aw3T8F, Ab3, u);
}